// Round 9
// baseline (210.134 us; speedup 1.0000x reference)
//
#include <hip/hip_runtime.h>
#include <math.h>

constexpr int NN  = 4096;   // nodes
constexpr int CC  = 256;    // channels
constexpr int EE0 = 65536;  // edges w/o self loops
constexpr int EE  = 69632;  // EE0 + NN
constexpr int KK  = 2048;   // pooled nodes
constexpr int PCAP = 1536;  // pair-chunk capacity in k_eadj

__device__ __forceinline__ void edge_ij(const int* __restrict__ ei, int e, int& i, int& j) {
    if (e < EE0) { i = ei[e]; j = ei[EE0 + e]; }
    else         { i = e - EE0; j = i; }
}

// ---------------- fused: edge count (CSR build) + wv precompute ----------------
__global__ __launch_bounds__(256) void k_init(const int* __restrict__ ei, int* cnt_i, int* cnt_j,
                                              const float* __restrict__ Wq, const float* __restrict__ bq,
                                              const float* __restrict__ gat_w, const float* __restrict__ gat_b,
                                              double* wv, double* consts, int EB) {
    if ((int)blockIdx.x < EB) {
        int e = blockIdx.x * 256 + threadIdx.x;
        if (e >= EE) return;
        int i, j; edge_ij(ei, e, i, j);
        atomicAdd(&cnt_i[i], 1);
        atomicAdd(&cnt_j[j], 1);
        return;
    }
    int k = blockIdx.x - EB, c = threadIdx.x;
    double s = (double)Wq[k * CC + c] * (double)gat_w[c];
    #pragma unroll
    for (int d = 32; d > 0; d >>= 1) s += __shfl_down(s, d, 64);
    __shared__ double red[4];
    if ((c & 63) == 0) red[c >> 6] = s;
    __syncthreads();
    if (c == 0) wv[k] = red[0] + red[1] + red[2] + red[3];
    if (k == 0 && c == 0) {
        double cb = 0.0;
        for (int q = 0; q < CC; ++q) cb += (double)bq[q] * (double)gat_w[q];
        consts[0] = cb + (double)gat_b[0];
    }
}

__global__ __launch_bounds__(1024) void k_scan(const int* cnt_i, int* off_i, int* pos_i,
                                               const int* cnt_j, int* off_j, int* pos_j) {
    const int* cnt = blockIdx.x ? cnt_j : cnt_i;
    int* off = blockIdx.x ? off_j : off_i;
    int* pos = blockIdx.x ? pos_j : pos_i;
    __shared__ int lds[1024];
    int t = threadIdx.x;
    int b = t * 4;
    int c0 = cnt[b], c1 = cnt[b + 1], c2 = cnt[b + 2], c3 = cnt[b + 3];
    int s = c0 + c1 + c2 + c3;
    lds[t] = s;
    __syncthreads();
    for (int d = 1; d < 1024; d <<= 1) {
        int add = (t >= d) ? lds[t - d] : 0;
        __syncthreads();
        lds[t] += add;
        __syncthreads();
    }
    int excl = lds[t] - s;
    int o0 = excl, o1 = o0 + c0, o2 = o1 + c1, o3 = o2 + c2;
    off[b] = o0; off[b + 1] = o1; off[b + 2] = o2; off[b + 3] = o3;
    pos[b] = o0; pos[b + 1] = o1; pos[b + 2] = o2; pos[b + 3] = o3;
    if (t == 1023) off[NN] = o3 + c3;
}

// scatter; also record ji[slot] = j for CSR-i slots (free here)
__global__ void k_scatter(const int* __restrict__ ei, int* pos_i, int* lst_i,
                          int* pos_j, int* lst_j, int* ji) {
    int e = blockIdx.x * blockDim.x + threadIdx.x;
    if (e >= EE) return;
    int i, j; edge_ij(ei, e, i, j);
    int pi = atomicAdd(&pos_i[i], 1);
    lst_i[pi] = e;
    ji[pi] = j;
    lst_j[atomicAdd(&pos_j[j], 1)] = e;
}

// fused: Xq-row max (registers only) -> alpha[n] = Xq[n].wv; beta[n] = x[n].gat_w[C:]
__global__ __launch_bounds__(256) void k_xqab(const float* __restrict__ x,
                                              const int* __restrict__ off_i, const int* __restrict__ ji,
                                              const double* __restrict__ wv, const float* __restrict__ gat_w,
                                              double* alpha, double* beta) {
    int n = blockIdx.x, t = threadIdx.x, g = t >> 6, l = t & 63;
    int s = off_i[n], e_ = off_i[n + 1];
    float4 m = make_float4(-INFINITY, -INFINITY, -INFINITY, -INFINITY);
    for (int p = s + g; p < e_; p += 4) {
        int j = ji[p];
        float4 v = ((const float4*)(x + (size_t)j * CC))[l];
        m.x = fmaxf(m.x, v.x); m.y = fmaxf(m.y, v.y);
        m.z = fmaxf(m.z, v.z); m.w = fmaxf(m.w, v.w);
    }
    __shared__ float4 red[4][64];
    red[g][l] = m;
    __syncthreads();
    if (g == 0) {
        float4 a = red[0][l], b = red[1][l], c2 = red[2][l], d4 = red[3][l];
        m.x = fmaxf(fmaxf(a.x, b.x), fmaxf(c2.x, d4.x));
        m.y = fmaxf(fmaxf(a.y, b.y), fmaxf(c2.y, d4.y));
        m.z = fmaxf(fmaxf(a.z, b.z), fmaxf(c2.z, d4.z));
        m.w = fmaxf(fmaxf(a.w, b.w), fmaxf(c2.w, d4.w));
        double alph = (double)m.x * wv[4 * l] + (double)m.y * wv[4 * l + 1]
                    + (double)m.z * wv[4 * l + 2] + (double)m.w * wv[4 * l + 3];
        float4 xn = ((const float4*)(x + (size_t)n * CC))[l];
        const float* gw2 = gat_w + CC;
        double bet = (double)xn.x * (double)gw2[4 * l] + (double)xn.y * (double)gw2[4 * l + 1]
                   + (double)xn.z * (double)gw2[4 * l + 2] + (double)xn.w * (double)gw2[4 * l + 3];
        #pragma unroll
        for (int d = 32; d > 0; d >>= 1) {
            alph += __shfl_down(alph, d, 64);
            bet  += __shfl_down(bet, d, 64);
        }
        if (l == 0) { alpha[n] = alph; beta[n] = bet; }
    }
}

// fused: leaky-relu scores + segment softmax + out-gather + LEConv dots
__global__ __launch_bounds__(256) void k_softout(const float* __restrict__ x,
                                                 const int* __restrict__ off_i, const int* __restrict__ lst_i,
                                                 const int* __restrict__ ji,
                                                 const double* __restrict__ alpha, const double* __restrict__ beta,
                                                 const double* __restrict__ consts,
                                                 const float* __restrict__ le1_w, const float* __restrict__ le1_b,
                                                 const float* __restrict__ le2_w,
                                                 const float* __restrict__ le3_w, const float* __restrict__ le3_b,
                                                 float* __restrict__ score32, double* __restrict__ out64,
                                                 double* a64, double* b64, double* l3v) {
    __shared__ double ssc[128];
    __shared__ double mz[2];
    __shared__ double red[4][CC];
    int n = blockIdx.x, t = threadIdx.x, g = t >> 6, l = t & 63;
    int s = off_i[n];
    int deg = off_i[n + 1] - s;
    double an = alpha[n] + consts[0];
    for (int p = t; p < deg; p += 256) {
        double v = an + beta[ji[s + p]];
        ssc[p] = v > 0.0 ? v : 0.2 * v;
    }
    __syncthreads();
    if (t < 64) {
        double m = -1e300;
        for (int p = l; p < deg; p += 64) m = fmax(m, ssc[p]);
        #pragma unroll
        for (int d = 32; d > 0; d >>= 1) m = fmax(m, __shfl_xor(m, d, 64));
        double z = 0.0;
        for (int p = l; p < deg; p += 64) z += exp(ssc[p] - m);
        #pragma unroll
        for (int d = 32; d > 0; d >>= 1) z += __shfl_xor(z, d, 64);
        if (l == 0) { mz[0] = m; mz[1] = 1.0 / z; }
    }
    __syncthreads();
    double m = mz[0], inv = mz[1];
    for (int p = t; p < deg; p += 256) {
        double sc_ = exp(ssc[p] - m) * inv;
        ssc[p] = sc_;
        score32[lst_i[s + p]] = (float)sc_;
    }
    __syncthreads();
    double a0 = 0, a1 = 0, a2 = 0, a3 = 0;
    for (int p = g; p < deg; p += 4) {
        double sc_ = ssc[p];
        float4 v = ((const float4*)(x + (size_t)ji[s + p] * CC))[l];
        a0 += sc_ * (double)v.x; a1 += sc_ * (double)v.y;
        a2 += sc_ * (double)v.z; a3 += sc_ * (double)v.w;
    }
    red[g][4 * l + 0] = a0; red[g][4 * l + 1] = a1;
    red[g][4 * l + 2] = a2; red[g][4 * l + 3] = a3;
    __syncthreads();
    if (g == 0) {
        double o0 = red[0][4 * l] + red[1][4 * l] + red[2][4 * l] + red[3][4 * l];
        double o1 = red[0][4 * l + 1] + red[1][4 * l + 1] + red[2][4 * l + 1] + red[3][4 * l + 1];
        double o2 = red[0][4 * l + 2] + red[1][4 * l + 2] + red[2][4 * l + 2] + red[3][4 * l + 2];
        double o3 = red[0][4 * l + 3] + red[1][4 * l + 3] + red[2][4 * l + 3] + red[3][4 * l + 3];
        double* orow = out64 + (size_t)n * CC + 4 * l;
        orow[0] = o0; orow[1] = o1; orow[2] = o2; orow[3] = o3;
        float4 w1 = ((const float4*)le1_w)[l];
        float4 w2 = ((const float4*)le2_w)[l];
        float4 w3 = ((const float4*)le3_w)[l];
        double s1 = o0 * (double)w1.x + o1 * (double)w1.y + o2 * (double)w1.z + o3 * (double)w1.w;
        double s2 = o0 * (double)w2.x + o1 * (double)w2.y + o2 * (double)w2.z + o3 * (double)w2.w;
        double s3 = o0 * (double)w3.x + o1 * (double)w3.y + o2 * (double)w3.z + o3 * (double)w3.w;
        #pragma unroll
        for (int d = 32; d > 0; d >>= 1) {
            s1 += __shfl_down(s1, d, 64);
            s2 += __shfl_down(s2, d, 64);
            s3 += __shfl_down(s3, d, 64);
        }
        if (l == 0) {
            a64[n] = s1 + (double)le1_b[0];
            b64[n] = s2;
            l3v[n] = s3 + (double)le3_b[0];
        }
    }
}

// zlog[n] = (sum_e a[j_e]) - deg*b[n] + l3[n]; wave per node
__global__ __launch_bounds__(256) void k_zlog(const int* __restrict__ off_i, const int* __restrict__ ji,
                                              const double* __restrict__ a64, const double* __restrict__ b64,
                                              const double* __restrict__ l3v, double* zlog) {
    int n = blockIdx.x * 4 + (threadIdx.x >> 6);
    int l = threadIdx.x & 63;
    int s = off_i[n], e_ = off_i[n + 1];
    double acc = 0.0;
    for (int p = s + l; p < e_; p += 64) acc += a64[ji[p]];
    #pragma unroll
    for (int d = 32; d > 0; d >>= 1) acc += __shfl_xor(acc, d, 64);
    if (l == 0) zlog[n] = acc - (double)(e_ - s) * b64[n] + l3v[n];
}

// rank-by-counting top-K (stable descending) = jax.lax.top_k order, fused x_out write
__global__ __launch_bounds__(256) void k_rank(const double* __restrict__ zlog,
                                              const double* __restrict__ out64,
                                              int* __restrict__ perm, int* __restrict__ n_idx,
                                              float* __restrict__ xout, float* __restrict__ operm) {
    int n = blockIdx.x, t = threadIdx.x;
    double zn = zlog[n];
    int cnt = 0;
    #pragma unroll
    for (int u = 0; u < NN / 256; ++u) {
        int m = t + u * 256;
        double zm = zlog[m];
        cnt += ((zm > zn) || (zm == zn && m < n)) ? 1 : 0;
    }
    #pragma unroll
    for (int d = 32; d > 0; d >>= 1) cnt += __shfl_down(cnt, d, 64);
    __shared__ int red[4];
    __shared__ int rr;
    if ((t & 63) == 0) red[t >> 6] = cnt;
    __syncthreads();
    if (t == 0) {
        int r = red[0] + red[1] + red[2] + red[3];
        rr = r;
        if (r < KK) {
            perm[r] = n;
            n_idx[n] = r;
            operm[r] = (float)n;
        }
    }
    __syncthreads();
    int r = rr;
    if (r < KK) {
        double fit = 1.0 / (1.0 + exp(-zn));
        xout[(size_t)r * CC + t] = (float)(out64[(size_t)n * CC + t] * fit);
    }
}

// per CSR-j slot: cv = (col = n_idx[i_e] (-1 if dropped), val = score[e]) packed;
// per CSR-i slot: si = score[lst_i[p]]
__global__ void k_colval(const int* __restrict__ ei, const int* __restrict__ lst_j,
                         const int* __restrict__ lst_i,
                         const int* __restrict__ n_idx, const float* __restrict__ score32,
                         int2* __restrict__ cv, float* __restrict__ si) {
    int p = blockIdx.x * 256 + threadIdx.x;
    if (p >= EE) return;
    int e = lst_j[p]; int i, j; edge_ij(ei, e, i, j);
    cv[p] = make_int2(n_idx[i], __float_as_int(score32[e]));
    si[p] = score32[lst_i[p]];
}

// Eadj[r,:] = sum_{e1: i=perm[r]} s1 * sum_{e2 in CSR-i[j_e1]} S[j_e2, :]  (3 levels)
// Latency-optimized: shuffle-scan + chunked pair list + flat virtual-slot streaming
// with explicit 4-way MLP (independent packed cv loads). 22KB LDS -> 7 blocks/CU.
__global__ __launch_bounds__(256) void k_eadj(const int* __restrict__ off_i, const int* __restrict__ ji,
                                              const float* __restrict__ si,
                                              const int* __restrict__ off_j,
                                              const int2* __restrict__ cv,
                                              const int* __restrict__ perm,
                                              float* __restrict__ Ead) {
    __shared__ float row[KK];      // 8 KB accumulator
    __shared__ int   sm0[128];     // CSR-i start of j1 per outer edge o
    __shared__ float ss1[128];     // score of outer edge o
    __shared__ int   sbase[129];   // exclusive offsets into pair space
    __shared__ int   swt[2];
    __shared__ int   pqv[PCAP];    // packed q0 | (qc<<20) per pair
    __shared__ float ps[PCAP];     // outer score per pair
    int r = blockIdx.x, t = threadIdx.x;
    int lane = t & 63, wid = t >> 6;
    float4 z4 = make_float4(0.f, 0.f, 0.f, 0.f);
    for (int c = t; c < KK / 4; c += 256) ((float4*)row)[c] = z4;
    int n = perm[r];
    int s = off_i[n];
    int deg = off_i[n + 1] - s;    // <= 128
    // phase A: outer-edge metadata + mid-level counts
    int cval = 0;
    if (t < deg) {
        int j1 = ji[s + t];
        ss1[t] = si[s + t];
        int m0 = off_i[j1];
        int m1 = off_i[j1 + 1];
        sm0[t] = m0;
        cval = m1 - m0;
    }
    // 2-wave shuffle inclusive scan (only waves 0,1 hold valid data)
    int sc = cval;
    #pragma unroll
    for (int d = 1; d < 64; d <<= 1) {
        int v = __shfl_up(sc, d, 64);
        if (lane >= d) sc += v;
    }
    if (wid == 0 && lane == 63) swt[0] = sc;
    __syncthreads();
    if (t < 128) {
        int add = (wid == 1) ? swt[0] : 0;
        sbase[t + 1] = sc + add;
        if (t == 0) sbase[0] = 0;
    }
    __syncthreads();
    int npairs = sbase[deg];
    for (int cb = 0; cb < npairs; cb += PCAP) {
        int cnt = min(PCAP, npairs - cb);
        // pair expansion: binary search outer o, fetch (q0,qc) of j2 (2x unrolled for MLP)
        for (int pp = t; pp < cnt; pp += 512) {
            {
                int gp = cb + pp;
                int lo = 0, hi = deg;
                while (hi - lo > 1) { int mid = (lo + hi) >> 1; if (sbase[mid] <= gp) lo = mid; else hi = mid; }
                int p = sm0[lo] + (gp - sbase[lo]);
                int j2 = ji[p];
                int q0 = off_j[j2];
                int qc = off_j[j2 + 1] - q0;
                pqv[pp] = q0 | (qc << 20);
                ps[pp] = ss1[lo];
            }
            int pp2 = pp + 256;
            if (pp2 < cnt) {
                int gp = cb + pp2;
                int lo = 0, hi = deg;
                while (hi - lo > 1) { int mid = (lo + hi) >> 1; if (sbase[mid] <= gp) lo = mid; else hi = mid; }
                int p = sm0[lo] + (gp - sbase[lo]);
                int j2 = ji[p];
                int q0 = off_j[j2];
                int qc = off_j[j2 + 1] - q0;
                pqv[pp2] = q0 | (qc << 20);
                ps[pp2] = ss1[lo];
            }
        }
        __syncthreads();
        // phase B: flat virtual slots (pair x 32 lanes), two offset passes cover qc<=64,
        // 4-way manual unroll -> 4 independent 8B loads in flight per thread per round
        int VS = cnt * 32;
        #pragma unroll
        for (int off = 0; off <= 32; off += 32) {
            for (int vb = 0; vb < VS; vb += 1024) {
                int   cols[4]; float vals[4]; bool act[4];
                #pragma unroll
                for (int u = 0; u < 4; ++u) {
                    int v = vb + u * 256 + t;
                    act[u] = false;
                    if (v < VS) {
                        int p = v >> 5;
                        int packed = pqv[p];
                        int qc = (int)((unsigned)packed >> 20);
                        int q = (v & 31) + off;
                        if (q < qc) {
                            int q0 = packed & 0xFFFFF;
                            int2 e = cv[q0 + q];
                            cols[u] = e.x;
                            vals[u] = __int_as_float(e.y) * ps[p];
                            act[u] = e.x >= 0;
                        }
                    }
                }
                #pragma unroll
                for (int u = 0; u < 4; ++u)
                    if (act[u]) atomicAdd(&row[cols[u]], vals[u]);
            }
        }
        // safety: qc > 64 tail (expected never for this graph)
        for (int p = t; p < cnt; p += 256) {
            int packed = pqv[p];
            int qc = (int)((unsigned)packed >> 20);
            if (qc > 64) {
                int q0 = packed & 0xFFFFF;
                float s1 = ps[p];
                for (int q = 64; q < qc; ++q) {
                    int2 e = cv[q0 + q];
                    if (e.x >= 0) atomicAdd(&row[e.x], s1 * __int_as_float(e.y));
                }
            }
        }
        __syncthreads();
    }
    float* __restrict__ erow = Ead + (size_t)r * KK;
    for (int c4 = t; c4 < KK / 4; c4 += 256) {
        float4 v = ((float4*)row)[c4];
        int base = c4 * 4;
        int dr = r - base;
        if (dr >= 0 && dr < 4) ((float*)&v)[dr] = 1.0f;
        ((float4*)erow)[c4] = v;
    }
}

extern "C" void kernel_launch(void* const* d_in, const int* in_sizes, int n_in,
                              void* d_out, int out_size, void* d_ws, size_t ws_size,
                              hipStream_t stream) {
    const float* x     = (const float*)d_in[0];
    const int*   ei    = (const int*)d_in[1];
    const float* Wq    = (const float*)d_in[2];
    const float* bq    = (const float*)d_in[3];
    const float* gat_w = (const float*)d_in[4];
    const float* gat_b = (const float*)d_in[5];
    const float* le1_w = (const float*)d_in[6];
    const float* le1_b = (const float*)d_in[7];
    const float* le2_w = (const float*)d_in[8];
    const float* le3_w = (const float*)d_in[9];
    const float* le3_b = (const float*)d_in[10];

    float* xout  = (float*)d_out;          // [K, C]
    float* Ead   = xout + (size_t)KK * CC; // [K, K]
    float* operm = Ead + (size_t)KK * KK;  // [K]

    char* w = (char*)d_ws;
    auto alloc = [&](size_t bytes) -> void* {
        void* p = (void*)w;
        w += (bytes + 255) & ~(size_t)255;
        return p;
    };
    float*  score32= (float*)alloc(EE * 4);
    double* alpha  = (double*)alloc(NN * 8);
    double* beta   = (double*)alloc(NN * 8);
    double* a64    = (double*)alloc(NN * 8);
    double* b64    = (double*)alloc(NN * 8);
    double* l3v    = (double*)alloc(NN * 8);
    double* zlog   = (double*)alloc(NN * 8);
    double* out64  = (double*)alloc((size_t)NN * CC * 8);
    double* wv     = (double*)alloc(CC * 8);
    double* consts = (double*)alloc(64);
    int* cnt_i = (int*)alloc(NN * 4);       // cnt_i, cnt_j adjacent: one memset
    int* cnt_j = (int*)alloc(NN * 4);
    int* off_i = (int*)alloc((NN + 1) * 4);
    int* pos_i = (int*)alloc(NN * 4);
    int* lst_i = (int*)alloc(EE * 4);
    int* off_j = (int*)alloc((NN + 1) * 4);
    int* pos_j = (int*)alloc(NN * 4);
    int* lst_j = (int*)alloc(EE * 4);
    int* ji    = (int*)alloc(EE * 4);
    float* si  = (float*)alloc(EE * 4);
    int* n_idx = (int*)alloc(NN * 4);
    int* perm  = (int*)alloc(KK * 4);
    int2* cv   = (int2*)alloc((size_t)EE * 8);

    hipMemsetAsync(cnt_i, 0, 2 * NN * 4 + 256, stream);  // cnt_i + cnt_j (adjacent, 256-pad)
    hipMemsetAsync(n_idx, 0xFF, NN * 4, stream);         // -1

    const int EB = (EE + 255) / 256;  // 272

    k_init<<<EB + CC, 256, 0, stream>>>(ei, cnt_i, cnt_j, Wq, bq, gat_w, gat_b, wv, consts, EB);
    k_scan<<<2, 1024, 0, stream>>>(cnt_i, off_i, pos_i, cnt_j, off_j, pos_j);
    k_scatter<<<EB, 256, 0, stream>>>(ei, pos_i, lst_i, pos_j, lst_j, ji);
    k_xqab<<<NN, 256, 0, stream>>>(x, off_i, ji, wv, gat_w, alpha, beta);
    k_softout<<<NN, 256, 0, stream>>>(x, off_i, lst_i, ji, alpha, beta, consts,
                                      le1_w, le1_b, le2_w, le3_w, le3_b,
                                      score32, out64, a64, b64, l3v);
    k_zlog<<<NN / 4, 256, 0, stream>>>(off_i, ji, a64, b64, l3v, zlog);
    k_rank<<<NN, 256, 0, stream>>>(zlog, out64, perm, n_idx, xout, operm);
    k_colval<<<EB, 256, 0, stream>>>(ei, lst_j, lst_i, n_idx, score32, cv, si);
    k_eadj<<<KK, 256, 0, stream>>>(off_i, ji, si, off_j, cv, perm, Ead);
}

// Round 10
// 178.070 us; speedup vs baseline: 1.1801x; 1.1801x over previous
//
#include <hip/hip_runtime.h>
#include <hip/hip_fp16.h>
#include <math.h>

constexpr int NN  = 4096;   // nodes
constexpr int CC  = 256;    // channels
constexpr int EE0 = 65536;  // edges w/o self loops
constexpr int EE  = 69632;  // EE0 + NN
constexpr int KK  = 2048;   // pooled nodes

__device__ __forceinline__ void edge_ij(const int* __restrict__ ei, int e, int& i, int& j) {
    if (e < EE0) { i = ei[e]; j = ei[EE0 + e]; }
    else         { i = e - EE0; j = i; }
}

// ---------------- fused: edge count (CSR build) + wv precompute ----------------
__global__ __launch_bounds__(256) void k_init(const int* __restrict__ ei, int* cnt_i, int* cnt_j,
                                              const float* __restrict__ Wq, const float* __restrict__ bq,
                                              const float* __restrict__ gat_w, const float* __restrict__ gat_b,
                                              double* wv, double* consts, int EB) {
    if ((int)blockIdx.x < EB) {
        int e = blockIdx.x * 256 + threadIdx.x;
        if (e >= EE) return;
        int i, j; edge_ij(ei, e, i, j);
        atomicAdd(&cnt_i[i], 1);
        atomicAdd(&cnt_j[j], 1);
        return;
    }
    int k = blockIdx.x - EB, c = threadIdx.x;
    double s = (double)Wq[k * CC + c] * (double)gat_w[c];
    #pragma unroll
    for (int d = 32; d > 0; d >>= 1) s += __shfl_down(s, d, 64);
    __shared__ double red[4];
    if ((c & 63) == 0) red[c >> 6] = s;
    __syncthreads();
    if (c == 0) wv[k] = red[0] + red[1] + red[2] + red[3];
    if (k == 0 && c == 0) {
        double cb = 0.0;
        for (int q = 0; q < CC; ++q) cb += (double)bq[q] * (double)gat_w[q];
        consts[0] = cb + (double)gat_b[0];
    }
}

__global__ __launch_bounds__(1024) void k_scan(const int* cnt_i, int* off_i, int* pos_i,
                                               const int* cnt_j, int* off_j, int* pos_j) {
    const int* cnt = blockIdx.x ? cnt_j : cnt_i;
    int* off = blockIdx.x ? off_j : off_i;
    int* pos = blockIdx.x ? pos_j : pos_i;
    __shared__ int lds[1024];
    int t = threadIdx.x;
    int b = t * 4;
    int c0 = cnt[b], c1 = cnt[b + 1], c2 = cnt[b + 2], c3 = cnt[b + 3];
    int s = c0 + c1 + c2 + c3;
    lds[t] = s;
    __syncthreads();
    for (int d = 1; d < 1024; d <<= 1) {
        int add = (t >= d) ? lds[t - d] : 0;
        __syncthreads();
        lds[t] += add;
        __syncthreads();
    }
    int excl = lds[t] - s;
    int o0 = excl, o1 = o0 + c0, o2 = o1 + c1, o3 = o2 + c2;
    off[b] = o0; off[b + 1] = o1; off[b + 2] = o2; off[b + 3] = o3;
    pos[b] = o0; pos[b + 1] = o1; pos[b + 2] = o2; pos[b + 3] = o3;
    if (t == 1023) off[NN] = o3 + c3;
}

// scatter; also record ji[slot] = j for CSR-i slots (free here)
__global__ void k_scatter(const int* __restrict__ ei, int* pos_i, int* lst_i,
                          int* pos_j, int* lst_j, int* ji) {
    int e = blockIdx.x * blockDim.x + threadIdx.x;
    if (e >= EE) return;
    int i, j; edge_ij(ei, e, i, j);
    int pi = atomicAdd(&pos_i[i], 1);
    lst_i[pi] = e;
    ji[pi] = j;
    lst_j[atomicAdd(&pos_j[j], 1)] = e;
}

// fused: Xq-row max (registers only) -> alpha[n] = Xq[n].wv; beta[n] = x[n].gat_w[C:]
__global__ __launch_bounds__(256) void k_xqab(const float* __restrict__ x,
                                              const int* __restrict__ off_i, const int* __restrict__ ji,
                                              const double* __restrict__ wv, const float* __restrict__ gat_w,
                                              double* alpha, double* beta) {
    int n = blockIdx.x, t = threadIdx.x, g = t >> 6, l = t & 63;
    int s = off_i[n], e_ = off_i[n + 1];
    float4 m = make_float4(-INFINITY, -INFINITY, -INFINITY, -INFINITY);
    for (int p = s + g; p < e_; p += 4) {
        int j = ji[p];
        float4 v = ((const float4*)(x + (size_t)j * CC))[l];
        m.x = fmaxf(m.x, v.x); m.y = fmaxf(m.y, v.y);
        m.z = fmaxf(m.z, v.z); m.w = fmaxf(m.w, v.w);
    }
    __shared__ float4 red[4][64];
    red[g][l] = m;
    __syncthreads();
    if (g == 0) {
        float4 a = red[0][l], b = red[1][l], c2 = red[2][l], d4 = red[3][l];
        m.x = fmaxf(fmaxf(a.x, b.x), fmaxf(c2.x, d4.x));
        m.y = fmaxf(fmaxf(a.y, b.y), fmaxf(c2.y, d4.y));
        m.z = fmaxf(fmaxf(a.z, b.z), fmaxf(c2.z, d4.z));
        m.w = fmaxf(fmaxf(a.w, b.w), fmaxf(c2.w, d4.w));
        double alph = (double)m.x * wv[4 * l] + (double)m.y * wv[4 * l + 1]
                    + (double)m.z * wv[4 * l + 2] + (double)m.w * wv[4 * l + 3];
        float4 xn = ((const float4*)(x + (size_t)n * CC))[l];
        const float* gw2 = gat_w + CC;
        double bet = (double)xn.x * (double)gw2[4 * l] + (double)xn.y * (double)gw2[4 * l + 1]
                   + (double)xn.z * (double)gw2[4 * l + 2] + (double)xn.w * (double)gw2[4 * l + 3];
        #pragma unroll
        for (int d = 32; d > 0; d >>= 1) {
            alph += __shfl_down(alph, d, 64);
            bet  += __shfl_down(bet, d, 64);
        }
        if (l == 0) { alpha[n] = alph; beta[n] = bet; }
    }
}

// fused: leaky-relu scores + segment softmax + out-gather + LEConv dots
__global__ __launch_bounds__(256) void k_softout(const float* __restrict__ x,
                                                 const int* __restrict__ off_i, const int* __restrict__ lst_i,
                                                 const int* __restrict__ ji,
                                                 const double* __restrict__ alpha, const double* __restrict__ beta,
                                                 const double* __restrict__ consts,
                                                 const float* __restrict__ le1_w, const float* __restrict__ le1_b,
                                                 const float* __restrict__ le2_w,
                                                 const float* __restrict__ le3_w, const float* __restrict__ le3_b,
                                                 float* __restrict__ score32, double* __restrict__ out64,
                                                 double* a64, double* b64, double* l3v) {
    __shared__ double ssc[128];
    __shared__ double mz[2];
    __shared__ double red[4][CC];
    int n = blockIdx.x, t = threadIdx.x, g = t >> 6, l = t & 63;
    int s = off_i[n];
    int deg = off_i[n + 1] - s;
    double an = alpha[n] + consts[0];
    for (int p = t; p < deg; p += 256) {
        double v = an + beta[ji[s + p]];
        ssc[p] = v > 0.0 ? v : 0.2 * v;
    }
    __syncthreads();
    if (t < 64) {
        double m = -1e300;
        for (int p = l; p < deg; p += 64) m = fmax(m, ssc[p]);
        #pragma unroll
        for (int d = 32; d > 0; d >>= 1) m = fmax(m, __shfl_xor(m, d, 64));
        double z = 0.0;
        for (int p = l; p < deg; p += 64) z += exp(ssc[p] - m);
        #pragma unroll
        for (int d = 32; d > 0; d >>= 1) z += __shfl_xor(z, d, 64);
        if (l == 0) { mz[0] = m; mz[1] = 1.0 / z; }
    }
    __syncthreads();
    double m = mz[0], inv = mz[1];
    for (int p = t; p < deg; p += 256) {
        double sc_ = exp(ssc[p] - m) * inv;
        ssc[p] = sc_;
        score32[lst_i[s + p]] = (float)sc_;
    }
    __syncthreads();
    double a0 = 0, a1 = 0, a2 = 0, a3 = 0;
    for (int p = g; p < deg; p += 4) {
        double sc_ = ssc[p];
        float4 v = ((const float4*)(x + (size_t)ji[s + p] * CC))[l];
        a0 += sc_ * (double)v.x; a1 += sc_ * (double)v.y;
        a2 += sc_ * (double)v.z; a3 += sc_ * (double)v.w;
    }
    red[g][4 * l + 0] = a0; red[g][4 * l + 1] = a1;
    red[g][4 * l + 2] = a2; red[g][4 * l + 3] = a3;
    __syncthreads();
    if (g == 0) {
        double o0 = red[0][4 * l] + red[1][4 * l] + red[2][4 * l] + red[3][4 * l];
        double o1 = red[0][4 * l + 1] + red[1][4 * l + 1] + red[2][4 * l + 1] + red[3][4 * l + 1];
        double o2 = red[0][4 * l + 2] + red[1][4 * l + 2] + red[2][4 * l + 2] + red[3][4 * l + 2];
        double o3 = red[0][4 * l + 3] + red[1][4 * l + 3] + red[2][4 * l + 3] + red[3][4 * l + 3];
        double* orow = out64 + (size_t)n * CC + 4 * l;
        orow[0] = o0; orow[1] = o1; orow[2] = o2; orow[3] = o3;
        float4 w1 = ((const float4*)le1_w)[l];
        float4 w2 = ((const float4*)le2_w)[l];
        float4 w3 = ((const float4*)le3_w)[l];
        double s1 = o0 * (double)w1.x + o1 * (double)w1.y + o2 * (double)w1.z + o3 * (double)w1.w;
        double s2 = o0 * (double)w2.x + o1 * (double)w2.y + o2 * (double)w2.z + o3 * (double)w2.w;
        double s3 = o0 * (double)w3.x + o1 * (double)w3.y + o2 * (double)w3.z + o3 * (double)w3.w;
        #pragma unroll
        for (int d = 32; d > 0; d >>= 1) {
            s1 += __shfl_down(s1, d, 64);
            s2 += __shfl_down(s2, d, 64);
            s3 += __shfl_down(s3, d, 64);
        }
        if (l == 0) {
            a64[n] = s1 + (double)le1_b[0];
            b64[n] = s2;
            l3v[n] = s3 + (double)le3_b[0];
        }
    }
}

// zlog[n] = (sum_e a[j_e]) - deg*b[n] + l3[n]; wave per node
__global__ __launch_bounds__(256) void k_zlog(const int* __restrict__ off_i, const int* __restrict__ ji,
                                              const double* __restrict__ a64, const double* __restrict__ b64,
                                              const double* __restrict__ l3v, double* zlog) {
    int n = blockIdx.x * 4 + (threadIdx.x >> 6);
    int l = threadIdx.x & 63;
    int s = off_i[n], e_ = off_i[n + 1];
    double acc = 0.0;
    for (int p = s + l; p < e_; p += 64) acc += a64[ji[p]];
    #pragma unroll
    for (int d = 32; d > 0; d >>= 1) acc += __shfl_xor(acc, d, 64);
    if (l == 0) zlog[n] = acc - (double)(e_ - s) * b64[n] + l3v[n];
}

// rank-by-counting top-K (stable descending) = jax.lax.top_k order, fused x_out write
// also initializes n_idx (kept -> rank, dropped -> -1): replaces a memset
__global__ __launch_bounds__(256) void k_rank(const double* __restrict__ zlog,
                                              const double* __restrict__ out64,
                                              int* __restrict__ perm, int* __restrict__ n_idx,
                                              float* __restrict__ xout, float* __restrict__ operm) {
    int n = blockIdx.x, t = threadIdx.x;
    double zn = zlog[n];
    int cnt = 0;
    #pragma unroll
    for (int u = 0; u < NN / 256; ++u) {
        int m = t + u * 256;
        double zm = zlog[m];
        cnt += ((zm > zn) || (zm == zn && m < n)) ? 1 : 0;
    }
    #pragma unroll
    for (int d = 32; d > 0; d >>= 1) cnt += __shfl_down(cnt, d, 64);
    __shared__ int red[4];
    __shared__ int rr;
    if ((t & 63) == 0) red[t >> 6] = cnt;
    __syncthreads();
    if (t == 0) {
        int r = red[0] + red[1] + red[2] + red[3];
        rr = r;
        n_idx[n] = (r < KK) ? r : -1;
        if (r < KK) {
            perm[r] = n;
            operm[r] = (float)n;
        }
    }
    __syncthreads();
    int r = rr;
    if (r < KK) {
        double fit = 1.0 / (1.0 + exp(-zn));
        xout[(size_t)r * CC + t] = (float)(out64[(size_t)n * CC + t] * fit);
    }
}

// per CSR-j slot: cv = (col = n_idx[i_e] (-1 if dropped), val = score[e]) packed;
// per CSR-i slot: si = score[lst_i[p]]
__global__ void k_colval(const int* __restrict__ ei, const int* __restrict__ lst_j,
                         const int* __restrict__ lst_i,
                         const int* __restrict__ n_idx, const float* __restrict__ score32,
                         int2* __restrict__ cv, float* __restrict__ si) {
    int p = blockIdx.x * 256 + threadIdx.x;
    if (p >= EE) return;
    int e = lst_j[p]; int i, j; edge_ij(ei, e, i, j);
    cv[p] = make_int2(n_idx[i], __float_as_int(score32[e]));
    si[p] = score32[lst_i[p]];
}

// ---------------- Eadj = S^T A S, two-pass dense-W (fp16), atomic-free ----------------
// W[m,:] = (A @ S)[m,:] = sum_{e: i_e=m} S[j_e,:], accumulated in 8KB LDS fp32, fp16 writeback
__global__ __launch_bounds__(256) void k_w(const int* __restrict__ off_i, const int* __restrict__ ji,
                                           const int* __restrict__ off_j, const int2* __restrict__ cv,
                                           __half* __restrict__ W) {
    __shared__ float row[KK];
    int m = blockIdx.x, t = threadIdx.x;
    float4 z4 = make_float4(0.f, 0.f, 0.f, 0.f);
    for (int c = t; c < KK / 4; c += 256) ((float4*)row)[c] = z4;
    __syncthreads();
    int s = off_i[m], e_ = off_i[m + 1];
    int grp = t >> 5, lane = t & 31;
    for (int p = s + grp; p < e_; p += 8) {
        int j = ji[p];
        int q0 = off_j[j], q1 = off_j[j + 1];
        for (int q = q0 + lane; q < q1; q += 32) {
            int2 e2 = cv[q];
            if (e2.x >= 0) atomicAdd(&row[e2.x], __int_as_float(e2.y));
        }
    }
    __syncthreads();
    // fp16 writeback: thread t owns cols [8t, 8t+8)
    float4 lo = ((float4*)row)[2 * t];
    float4 hi = ((float4*)row)[2 * t + 1];
    __half2 h[4];
    h[0] = __floats2half2_rn(lo.x, lo.y);
    h[1] = __floats2half2_rn(lo.z, lo.w);
    h[2] = __floats2half2_rn(hi.x, hi.y);
    h[3] = __floats2half2_rn(hi.z, hi.w);
    *(float4*)(W + (size_t)m * KK + 8 * t) = *(float4*)h;
}

// Eadj[r, tile*512 .. +512) = sum_{e1: i=perm[r]} score[e1] * W[j_e1, tile-slice]
// tile = blockIdx.x % 4 -> with round-robin blockIdx->XCD, tile t maps to XCDs {t, t+4};
// per-XCD W working set = 4096 x 512 x 2B = 4MB = one XCD's L2. Diag forced to 1.
__global__ __launch_bounds__(256) void k_erow(const int* __restrict__ off_i, const int* __restrict__ ji,
                                              const float* __restrict__ si,
                                              const int* __restrict__ perm,
                                              const __half* __restrict__ W,
                                              float* __restrict__ Ead) {
    __shared__ int   sj[128];
    __shared__ float ss[128];
    int b = blockIdx.x;
    int tile = b & 3;
    int r = b >> 2;
    int t = threadIdx.x;
    int n = perm[r];
    int s = off_i[n];
    int deg = off_i[n + 1] - s;
    if (t < deg) { sj[t] = ji[s + t]; ss[t] = si[s + t]; }
    __syncthreads();
    int c2 = (tile << 9) + 2 * t;   // this thread's two columns
    float ax = 0.f, ay = 0.f;
    int p = 0;
    for (; p + 4 <= deg; p += 4) {
        __half2 w0 = *(const __half2*)(W + (size_t)sj[p + 0] * KK + c2);
        __half2 w1 = *(const __half2*)(W + (size_t)sj[p + 1] * KK + c2);
        __half2 w2 = *(const __half2*)(W + (size_t)sj[p + 2] * KK + c2);
        __half2 w3 = *(const __half2*)(W + (size_t)sj[p + 3] * KK + c2);
        float s0 = ss[p + 0], s1 = ss[p + 1], s2 = ss[p + 2], s3 = ss[p + 3];
        float2 f0 = __half22float2(w0), f1 = __half22float2(w1);
        float2 f2 = __half22float2(w2), f3 = __half22float2(w3);
        ax += s0 * f0.x + s1 * f1.x + s2 * f2.x + s3 * f3.x;
        ay += s0 * f0.y + s1 * f1.y + s2 * f2.y + s3 * f3.y;
    }
    for (; p < deg; ++p) {
        __half2 w0 = *(const __half2*)(W + (size_t)sj[p] * KK + c2);
        float s0 = ss[p];
        float2 f0 = __half22float2(w0);
        ax += s0 * f0.x;
        ay += s0 * f0.y;
    }
    int dr = r - c2;
    if (dr == 0) ax = 1.0f;
    else if (dr == 1) ay = 1.0f;
    *(float2*)(Ead + (size_t)r * KK + c2) = make_float2(ax, ay);
}

extern "C" void kernel_launch(void* const* d_in, const int* in_sizes, int n_in,
                              void* d_out, int out_size, void* d_ws, size_t ws_size,
                              hipStream_t stream) {
    const float* x     = (const float*)d_in[0];
    const int*   ei    = (const int*)d_in[1];
    const float* Wq    = (const float*)d_in[2];
    const float* bq    = (const float*)d_in[3];
    const float* gat_w = (const float*)d_in[4];
    const float* gat_b = (const float*)d_in[5];
    const float* le1_w = (const float*)d_in[6];
    const float* le1_b = (const float*)d_in[7];
    const float* le2_w = (const float*)d_in[8];
    const float* le3_w = (const float*)d_in[9];
    const float* le3_b = (const float*)d_in[10];

    float* xout  = (float*)d_out;          // [K, C]
    float* Ead   = xout + (size_t)KK * CC; // [K, K]
    float* operm = Ead + (size_t)KK * KK;  // [K]

    char* w = (char*)d_ws;
    auto alloc = [&](size_t bytes) -> void* {
        void* p = (void*)w;
        w += (bytes + 255) & ~(size_t)255;
        return p;
    };
    float*  score32= (float*)alloc(EE * 4);
    double* alpha  = (double*)alloc(NN * 8);
    double* beta   = (double*)alloc(NN * 8);
    double* a64    = (double*)alloc(NN * 8);
    double* b64    = (double*)alloc(NN * 8);
    double* l3v    = (double*)alloc(NN * 8);
    double* zlog   = (double*)alloc(NN * 8);
    double* out64  = (double*)alloc((size_t)NN * CC * 8);
    double* wv     = (double*)alloc(CC * 8);
    double* consts = (double*)alloc(64);
    int* cnt_i = (int*)alloc(NN * 4);       // cnt_i, cnt_j adjacent: one memset
    int* cnt_j = (int*)alloc(NN * 4);
    int* off_i = (int*)alloc((NN + 1) * 4);
    int* pos_i = (int*)alloc(NN * 4);
    int* lst_i = (int*)alloc(EE * 4);
    int* off_j = (int*)alloc((NN + 1) * 4);
    int* pos_j = (int*)alloc(NN * 4);
    int* lst_j = (int*)alloc(EE * 4);
    int* ji    = (int*)alloc(EE * 4);
    float* si  = (float*)alloc(EE * 4);
    int* n_idx = (int*)alloc(NN * 4);
    int* perm  = (int*)alloc(KK * 4);
    int2* cv   = (int2*)alloc((size_t)EE * 8);
    __half* Wbuf = (__half*)alloc((size_t)NN * KK * 2);   // 16 MB fp16

    hipMemsetAsync(cnt_i, 0, 2 * NN * 4 + 256, stream);  // cnt_i + cnt_j (adjacent, 256-pad)

    const int EB = (EE + 255) / 256;  // 272

    k_init<<<EB + CC, 256, 0, stream>>>(ei, cnt_i, cnt_j, Wq, bq, gat_w, gat_b, wv, consts, EB);
    k_scan<<<2, 1024, 0, stream>>>(cnt_i, off_i, pos_i, cnt_j, off_j, pos_j);
    k_scatter<<<EB, 256, 0, stream>>>(ei, pos_i, lst_i, pos_j, lst_j, ji);
    k_xqab<<<NN, 256, 0, stream>>>(x, off_i, ji, wv, gat_w, alpha, beta);
    k_softout<<<NN, 256, 0, stream>>>(x, off_i, lst_i, ji, alpha, beta, consts,
                                      le1_w, le1_b, le2_w, le3_w, le3_b,
                                      score32, out64, a64, b64, l3v);
    k_zlog<<<NN / 4, 256, 0, stream>>>(off_i, ji, a64, b64, l3v, zlog);
    k_rank<<<NN, 256, 0, stream>>>(zlog, out64, perm, n_idx, xout, operm);
    k_colval<<<EB, 256, 0, stream>>>(ei, lst_j, lst_i, n_idx, score32, cv, si);
    k_w<<<NN, 256, 0, stream>>>(off_i, ji, off_j, cv, Wbuf);
    k_erow<<<KK * 4, 256, 0, stream>>>(off_i, ji, si, perm, Wbuf, Ead);
}

// Round 11
// 171.591 us; speedup vs baseline: 1.2246x; 1.0378x over previous
//
#include <hip/hip_runtime.h>
#include <hip/hip_fp16.h>
#include <math.h>

constexpr int NN  = 4096;   // nodes
constexpr int CC  = 256;    // channels
constexpr int EE0 = 65536;  // edges w/o self loops
constexpr int EE  = 69632;  // EE0 + NN
constexpr int KK  = 2048;   // pooled nodes

__device__ __forceinline__ void edge_ij(const int* __restrict__ ei, int e, int& i, int& j) {
    if (e < EE0) { i = ei[e]; j = ei[EE0 + e]; }
    else         { i = e - EE0; j = i; }
}

// ---- fused init: edge count (CSR) + wv precompute + beta[n] = x[n].gat_w[C:] ----
// blocks [0,EB): count | [EB,EB+CC): wv | [EB+CC, EB+CC+NN/4): beta (4 nodes/block)
__global__ __launch_bounds__(256) void k_init(const int* __restrict__ ei, int* cnt_i, int* cnt_j,
                                              const float* __restrict__ x,
                                              const float* __restrict__ Wq, const float* __restrict__ bq,
                                              const float* __restrict__ gat_w, const float* __restrict__ gat_b,
                                              double* wv, double* consts, double* beta, int EB) {
    int b = blockIdx.x, t = threadIdx.x;
    if (b < EB) {
        int e = b * 256 + t;
        if (e >= EE) return;
        int i, j; edge_ij(ei, e, i, j);
        atomicAdd(&cnt_i[i], 1);
        atomicAdd(&cnt_j[j], 1);
        return;
    }
    if (b < EB + CC) {
        int k = b - EB, c = t;
        double s = (double)Wq[k * CC + c] * (double)gat_w[c];
        #pragma unroll
        for (int d = 32; d > 0; d >>= 1) s += __shfl_down(s, d, 64);
        __shared__ double red[4];
        if ((c & 63) == 0) red[c >> 6] = s;
        __syncthreads();
        if (c == 0) wv[k] = red[0] + red[1] + red[2] + red[3];
        if (k == 0 && c == 0) {
            double cb = 0.0;
            for (int q = 0; q < CC; ++q) cb += (double)bq[q] * (double)gat_w[q];
            consts[0] = cb + (double)gat_b[0];
        }
        return;
    }
    // beta blocks
    int idx = b - (EB + CC);
    int n = idx * 4 + (t >> 6);
    int l = t & 63;
    float4 xn = ((const float4*)(x + (size_t)n * CC))[l];
    const float* gw2 = gat_w + CC;
    double bet = (double)xn.x * (double)gw2[4 * l] + (double)xn.y * (double)gw2[4 * l + 1]
               + (double)xn.z * (double)gw2[4 * l + 2] + (double)xn.w * (double)gw2[4 * l + 3];
    #pragma unroll
    for (int d = 32; d > 0; d >>= 1) bet += __shfl_down(bet, d, 64);
    if (l == 0) beta[n] = bet;
}

__global__ __launch_bounds__(1024) void k_scan(const int* cnt_i, int* off_i, int* pos_i,
                                               const int* cnt_j, int* off_j, int* pos_j) {
    const int* cnt = blockIdx.x ? cnt_j : cnt_i;
    int* off = blockIdx.x ? off_j : off_i;
    int* pos = blockIdx.x ? pos_j : pos_i;
    __shared__ int lds[1024];
    int t = threadIdx.x;
    int b = t * 4;
    int c0 = cnt[b], c1 = cnt[b + 1], c2 = cnt[b + 2], c3 = cnt[b + 3];
    int s = c0 + c1 + c2 + c3;
    lds[t] = s;
    __syncthreads();
    for (int d = 1; d < 1024; d <<= 1) {
        int add = (t >= d) ? lds[t - d] : 0;
        __syncthreads();
        lds[t] += add;
        __syncthreads();
    }
    int excl = lds[t] - s;
    int o0 = excl, o1 = o0 + c0, o2 = o1 + c1, o3 = o2 + c2;
    off[b] = o0; off[b + 1] = o1; off[b + 2] = o2; off[b + 3] = o3;
    pos[b] = o0; pos[b + 1] = o1; pos[b + 2] = o2; pos[b + 3] = o3;
    if (t == 1023) off[NN] = o3 + c3;
}

// scatter; also record ji[slot] = j for CSR-i slots
__global__ void k_scatter(const int* __restrict__ ei, int* pos_i, int* lst_i,
                          int* pos_j, int* lst_j, int* ji) {
    int e = blockIdx.x * blockDim.x + threadIdx.x;
    if (e >= EE) return;
    int i, j; edge_ij(ei, e, i, j);
    int pi = atomicAdd(&pos_i[i], 1);
    lst_i[pi] = e;
    ji[pi] = j;
    lst_j[atomicAdd(&pos_j[j], 1)] = e;
}

// ---- fused attention: gather-max -> alpha -> leaky-relu+softmax -> out-gather -> LEConv dots ----
// One block per node; both gathers share staged sj and L2-warm x rows.
__global__ __launch_bounds__(256) void k_attn(const float* __restrict__ x,
                                              const int* __restrict__ off_i, const int* __restrict__ lst_i,
                                              const int* __restrict__ ji,
                                              const double* __restrict__ wv, const double* __restrict__ beta,
                                              const double* __restrict__ consts,
                                              const float* __restrict__ le1_w, const float* __restrict__ le1_b,
                                              const float* __restrict__ le2_w,
                                              const float* __restrict__ le3_w, const float* __restrict__ le3_b,
                                              float* __restrict__ score32, float* __restrict__ out32,
                                              double* a64, double* b64, double* l3v) {
    __shared__ int    sj[128];
    __shared__ double ssc[128];
    __shared__ double sAlpha;
    __shared__ double mz[2];
    __shared__ double red[4][CC];          // 8 KB, reused by both reduce phases
    int n = blockIdx.x, t = threadIdx.x, g = t >> 6, l = t & 63;
    int s = off_i[n];
    int deg = off_i[n + 1] - s;            // <= 128
    if (t < deg) sj[t] = ji[s + t];
    __syncthreads();
    // phase 1: per-channel max over neighbor rows (2x unrolled -> 2 loads in flight)
    float4 m = make_float4(-INFINITY, -INFINITY, -INFINITY, -INFINITY);
    for (int p = g; p < deg; p += 8) {
        float4 v0 = ((const float4*)(x + (size_t)sj[p] * CC))[l];
        if (p + 4 < deg) {
            float4 v1 = ((const float4*)(x + (size_t)sj[p + 4] * CC))[l];
            m.x = fmaxf(m.x, v1.x); m.y = fmaxf(m.y, v1.y);
            m.z = fmaxf(m.z, v1.z); m.w = fmaxf(m.w, v1.w);
        }
        m.x = fmaxf(m.x, v0.x); m.y = fmaxf(m.y, v0.y);
        m.z = fmaxf(m.z, v0.z); m.w = fmaxf(m.w, v0.w);
    }
    ((float4*)red[g])[l] = m;
    __syncthreads();
    if (g == 0) {
        float4 a = ((float4*)red[0])[l], b = ((float4*)red[1])[l];
        float4 c2 = ((float4*)red[2])[l], d4 = ((float4*)red[3])[l];
        m.x = fmaxf(fmaxf(a.x, b.x), fmaxf(c2.x, d4.x));
        m.y = fmaxf(fmaxf(a.y, b.y), fmaxf(c2.y, d4.y));
        m.z = fmaxf(fmaxf(a.z, b.z), fmaxf(c2.z, d4.z));
        m.w = fmaxf(fmaxf(a.w, b.w), fmaxf(c2.w, d4.w));
        double alph = (double)m.x * wv[4 * l] + (double)m.y * wv[4 * l + 1]
                    + (double)m.z * wv[4 * l + 2] + (double)m.w * wv[4 * l + 3];
        #pragma unroll
        for (int d = 32; d > 0; d >>= 1) alph += __shfl_down(alph, d, 64);
        if (l == 0) sAlpha = alph + consts[0];
    }
    __syncthreads();
    // phase 2: leaky-relu scores + segment softmax
    double an = sAlpha;
    for (int p = t; p < deg; p += 256) {
        double v = an + beta[sj[p]];
        ssc[p] = v > 0.0 ? v : 0.2 * v;
    }
    __syncthreads();
    if (t < 64) {
        double mm = -1e300;
        for (int p = l; p < deg; p += 64) mm = fmax(mm, ssc[p]);
        #pragma unroll
        for (int d = 32; d > 0; d >>= 1) mm = fmax(mm, __shfl_xor(mm, d, 64));
        double z = 0.0;
        for (int p = l; p < deg; p += 64) z += exp(ssc[p] - mm);
        #pragma unroll
        for (int d = 32; d > 0; d >>= 1) z += __shfl_xor(z, d, 64);
        if (l == 0) { mz[0] = mm; mz[1] = 1.0 / z; }
    }
    __syncthreads();
    double mm = mz[0], inv = mz[1];
    for (int p = t; p < deg; p += 256) {
        double sc_ = exp(ssc[p] - mm) * inv;
        ssc[p] = sc_;
        score32[lst_i[s + p]] = (float)sc_;
    }
    __syncthreads();
    // phase 3: out-gather (L2-warm rows, 2x unrolled) + LEConv dots
    double a0 = 0, a1 = 0, a2 = 0, a3 = 0;
    for (int p = g; p < deg; p += 8) {
        double sc0 = ssc[p];
        float4 v0 = ((const float4*)(x + (size_t)sj[p] * CC))[l];
        if (p + 4 < deg) {
            double sc1 = ssc[p + 4];
            float4 v1 = ((const float4*)(x + (size_t)sj[p + 4] * CC))[l];
            a0 += sc1 * (double)v1.x; a1 += sc1 * (double)v1.y;
            a2 += sc1 * (double)v1.z; a3 += sc1 * (double)v1.w;
        }
        a0 += sc0 * (double)v0.x; a1 += sc0 * (double)v0.y;
        a2 += sc0 * (double)v0.z; a3 += sc0 * (double)v0.w;
    }
    red[g][4 * l + 0] = a0; red[g][4 * l + 1] = a1;
    red[g][4 * l + 2] = a2; red[g][4 * l + 3] = a3;
    __syncthreads();
    if (g == 0) {
        double o0 = red[0][4 * l] + red[1][4 * l] + red[2][4 * l] + red[3][4 * l];
        double o1 = red[0][4 * l + 1] + red[1][4 * l + 1] + red[2][4 * l + 1] + red[3][4 * l + 1];
        double o2 = red[0][4 * l + 2] + red[1][4 * l + 2] + red[2][4 * l + 2] + red[3][4 * l + 2];
        double o3 = red[0][4 * l + 3] + red[1][4 * l + 3] + red[2][4 * l + 3] + red[3][4 * l + 3];
        ((float4*)(out32 + (size_t)n * CC))[l] = make_float4((float)o0, (float)o1, (float)o2, (float)o3);
        float4 w1 = ((const float4*)le1_w)[l];
        float4 w2 = ((const float4*)le2_w)[l];
        float4 w3 = ((const float4*)le3_w)[l];
        double s1 = o0 * (double)w1.x + o1 * (double)w1.y + o2 * (double)w1.z + o3 * (double)w1.w;
        double s2 = o0 * (double)w2.x + o1 * (double)w2.y + o2 * (double)w2.z + o3 * (double)w2.w;
        double s3 = o0 * (double)w3.x + o1 * (double)w3.y + o2 * (double)w3.z + o3 * (double)w3.w;
        #pragma unroll
        for (int d = 32; d > 0; d >>= 1) {
            s1 += __shfl_down(s1, d, 64);
            s2 += __shfl_down(s2, d, 64);
            s3 += __shfl_down(s3, d, 64);
        }
        if (l == 0) {
            a64[n] = s1 + (double)le1_b[0];
            b64[n] = s2;
            l3v[n] = s3 + (double)le3_b[0];
        }
    }
}

// zlog[n] = (sum_e a[j_e]) - deg*b[n] + l3[n]; wave per node
__global__ __launch_bounds__(256) void k_zlog(const int* __restrict__ off_i, const int* __restrict__ ji,
                                              const double* __restrict__ a64, const double* __restrict__ b64,
                                              const double* __restrict__ l3v, double* zlog) {
    int n = blockIdx.x * 4 + (threadIdx.x >> 6);
    int l = threadIdx.x & 63;
    int s = off_i[n], e_ = off_i[n + 1];
    double acc = 0.0;
    for (int p = s + l; p < e_; p += 64) acc += a64[ji[p]];
    #pragma unroll
    for (int d = 32; d > 0; d >>= 1) acc += __shfl_xor(acc, d, 64);
    if (l == 0) zlog[n] = acc - (double)(e_ - s) * b64[n] + l3v[n];
}

// rank-by-counting top-K (stable descending) = jax.lax.top_k order, fused x_out write
__global__ __launch_bounds__(256) void k_rank(const double* __restrict__ zlog,
                                              const float* __restrict__ out32,
                                              int* __restrict__ perm, int* __restrict__ n_idx,
                                              float* __restrict__ xout, float* __restrict__ operm) {
    int n = blockIdx.x, t = threadIdx.x;
    double zn = zlog[n];
    int cnt = 0;
    #pragma unroll
    for (int u = 0; u < NN / 256; ++u) {
        int m = t + u * 256;
        double zm = zlog[m];
        cnt += ((zm > zn) || (zm == zn && m < n)) ? 1 : 0;
    }
    #pragma unroll
    for (int d = 32; d > 0; d >>= 1) cnt += __shfl_down(cnt, d, 64);
    __shared__ int red[4];
    __shared__ int rr;
    if ((t & 63) == 0) red[t >> 6] = cnt;
    __syncthreads();
    if (t == 0) {
        int r = red[0] + red[1] + red[2] + red[3];
        rr = r;
        n_idx[n] = (r < KK) ? r : -1;
        if (r < KK) {
            perm[r] = n;
            operm[r] = (float)n;
        }
    }
    __syncthreads();
    int r = rr;
    if (r < KK) {
        double fit = 1.0 / (1.0 + exp(-zn));
        xout[(size_t)r * CC + t] = (float)((double)out32[(size_t)n * CC + t] * fit);
    }
}

// per CSR-j slot: cv = (col = n_idx[i_e] (-1 if dropped), val = score[e]) packed;
// per CSR-i slot: si = score[lst_i[p]]
__global__ void k_colval(const int* __restrict__ ei, const int* __restrict__ lst_j,
                         const int* __restrict__ lst_i,
                         const int* __restrict__ n_idx, const float* __restrict__ score32,
                         int2* __restrict__ cv, float* __restrict__ si) {
    int p = blockIdx.x * 256 + threadIdx.x;
    if (p >= EE) return;
    int e = lst_j[p]; int i, j; edge_ij(ei, e, i, j);
    cv[p] = make_int2(n_idx[i], __float_as_int(score32[e]));
    si[p] = score32[lst_i[p]];
}

// ---------------- Eadj = S^T A S, two-pass dense-W (fp16), atomic-free ----------------
__global__ __launch_bounds__(256) void k_w(const int* __restrict__ off_i, const int* __restrict__ ji,
                                           const int* __restrict__ off_j, const int2* __restrict__ cv,
                                           __half* __restrict__ W) {
    __shared__ float row[KK];
    int m = blockIdx.x, t = threadIdx.x;
    float4 z4 = make_float4(0.f, 0.f, 0.f, 0.f);
    for (int c = t; c < KK / 4; c += 256) ((float4*)row)[c] = z4;
    __syncthreads();
    int s = off_i[m], e_ = off_i[m + 1];
    int grp = t >> 5, lane = t & 31;
    for (int p = s + grp; p < e_; p += 8) {
        int j = ji[p];
        int q0 = off_j[j], q1 = off_j[j + 1];
        for (int q = q0 + lane; q < q1; q += 32) {
            int2 e2 = cv[q];
            if (e2.x >= 0) atomicAdd(&row[e2.x], __int_as_float(e2.y));
        }
    }
    __syncthreads();
    float4 lo = ((float4*)row)[2 * t];
    float4 hi = ((float4*)row)[2 * t + 1];
    __half2 h[4];
    h[0] = __floats2half2_rn(lo.x, lo.y);
    h[1] = __floats2half2_rn(lo.z, lo.w);
    h[2] = __floats2half2_rn(hi.x, hi.y);
    h[3] = __floats2half2_rn(hi.z, hi.w);
    *(float4*)(W + (size_t)m * KK + 8 * t) = *(float4*)h;
}

// Eadj[r, tile*512 .. +512): tile = blockIdx % 4 -> per-XCD W slice = 4MB = L2-resident
__global__ __launch_bounds__(256) void k_erow(const int* __restrict__ off_i, const int* __restrict__ ji,
                                              const float* __restrict__ si,
                                              const int* __restrict__ perm,
                                              const __half* __restrict__ W,
                                              float* __restrict__ Ead) {
    __shared__ int   sj[128];
    __shared__ float ss[128];
    int b = blockIdx.x;
    int tile = b & 3;
    int r = b >> 2;
    int t = threadIdx.x;
    int n = perm[r];
    int s = off_i[n];
    int deg = off_i[n + 1] - s;
    if (t < deg) { sj[t] = ji[s + t]; ss[t] = si[s + t]; }
    __syncthreads();
    int c2 = (tile << 9) + 2 * t;
    float ax = 0.f, ay = 0.f;
    int p = 0;
    for (; p + 4 <= deg; p += 4) {
        __half2 w0 = *(const __half2*)(W + (size_t)sj[p + 0] * KK + c2);
        __half2 w1 = *(const __half2*)(W + (size_t)sj[p + 1] * KK + c2);
        __half2 w2 = *(const __half2*)(W + (size_t)sj[p + 2] * KK + c2);
        __half2 w3 = *(const __half2*)(W + (size_t)sj[p + 3] * KK + c2);
        float s0 = ss[p + 0], s1 = ss[p + 1], s2 = ss[p + 2], s3 = ss[p + 3];
        float2 f0 = __half22float2(w0), f1 = __half22float2(w1);
        float2 f2 = __half22float2(w2), f3 = __half22float2(w3);
        ax += s0 * f0.x + s1 * f1.x + s2 * f2.x + s3 * f3.x;
        ay += s0 * f0.y + s1 * f1.y + s2 * f2.y + s3 * f3.y;
    }
    for (; p < deg; ++p) {
        __half2 w0 = *(const __half2*)(W + (size_t)sj[p] * KK + c2);
        float s0 = ss[p];
        float2 f0 = __half22float2(w0);
        ax += s0 * f0.x;
        ay += s0 * f0.y;
    }
    int dr = r - c2;
    if (dr == 0) ax = 1.0f;
    else if (dr == 1) ay = 1.0f;
    *(float2*)(Ead + (size_t)r * KK + c2) = make_float2(ax, ay);
}

extern "C" void kernel_launch(void* const* d_in, const int* in_sizes, int n_in,
                              void* d_out, int out_size, void* d_ws, size_t ws_size,
                              hipStream_t stream) {
    const float* x     = (const float*)d_in[0];
    const int*   ei    = (const int*)d_in[1];
    const float* Wq    = (const float*)d_in[2];
    const float* bq    = (const float*)d_in[3];
    const float* gat_w = (const float*)d_in[4];
    const float* gat_b = (const float*)d_in[5];
    const float* le1_w = (const float*)d_in[6];
    const float* le1_b = (const float*)d_in[7];
    const float* le2_w = (const float*)d_in[8];
    const float* le3_w = (const float*)d_in[9];
    const float* le3_b = (const float*)d_in[10];

    float* xout  = (float*)d_out;          // [K, C]
    float* Ead   = xout + (size_t)KK * CC; // [K, K]
    float* operm = Ead + (size_t)KK * KK;  // [K]

    char* w = (char*)d_ws;
    auto alloc = [&](size_t bytes) -> void* {
        void* p = (void*)w;
        w += (bytes + 255) & ~(size_t)255;
        return p;
    };
    float*  score32= (float*)alloc(EE * 4);
    double* beta   = (double*)alloc(NN * 8);
    double* a64    = (double*)alloc(NN * 8);
    double* b64    = (double*)alloc(NN * 8);
    double* l3v    = (double*)alloc(NN * 8);
    double* zlog   = (double*)alloc(NN * 8);
    float*  out32  = (float*)alloc((size_t)NN * CC * 4);
    double* wv     = (double*)alloc(CC * 8);
    double* consts = (double*)alloc(64);
    int* cnt_i = (int*)alloc(NN * 4);       // cnt_i, cnt_j adjacent: one memset
    int* cnt_j = (int*)alloc(NN * 4);
    int* off_i = (int*)alloc((NN + 1) * 4);
    int* pos_i = (int*)alloc(NN * 4);
    int* lst_i = (int*)alloc(EE * 4);
    int* off_j = (int*)alloc((NN + 1) * 4);
    int* pos_j = (int*)alloc(NN * 4);
    int* lst_j = (int*)alloc(EE * 4);
    int* ji    = (int*)alloc(EE * 4);
    float* si  = (float*)alloc(EE * 4);
    int* n_idx = (int*)alloc(NN * 4);
    int* perm  = (int*)alloc(KK * 4);
    int2* cv   = (int2*)alloc((size_t)EE * 8);
    __half* Wbuf = (__half*)alloc((size_t)NN * KK * 2);   // 16 MB fp16

    hipMemsetAsync(cnt_i, 0, 2 * NN * 4 + 256, stream);  // cnt_i + cnt_j

    const int EB = (EE + 255) / 256;  // 272

    k_init<<<EB + CC + NN / 4, 256, 0, stream>>>(ei, cnt_i, cnt_j, x, Wq, bq, gat_w, gat_b,
                                                 wv, consts, beta, EB);
    k_scan<<<2, 1024, 0, stream>>>(cnt_i, off_i, pos_i, cnt_j, off_j, pos_j);
    k_scatter<<<EB, 256, 0, stream>>>(ei, pos_i, lst_i, pos_j, lst_j, ji);
    k_attn<<<NN, 256, 0, stream>>>(x, off_i, lst_i, ji, wv, beta, consts,
                                   le1_w, le1_b, le2_w, le3_w, le3_b,
                                   score32, out32, a64, b64, l3v);
    k_zlog<<<NN / 4, 256, 0, stream>>>(off_i, ji, a64, b64, l3v, zlog);
    k_rank<<<NN, 256, 0, stream>>>(zlog, out32, perm, n_idx, xout, operm);
    k_colval<<<EB, 256, 0, stream>>>(ei, lst_j, lst_i, n_idx, score32, cv, si);
    k_w<<<NN, 256, 0, stream>>>(off_i, ji, off_j, cv, Wbuf);
    k_erow<<<KK * 4, 256, 0, stream>>>(off_i, ji, si, perm, Wbuf, Ead);
}